// Round 7
// baseline (96.516 us; speedup 1.0000x reference)
//
#include <hip/hip_runtime.h>

// Problem constants (fixed by the reference):
//   B=8, N=256, IN_F=64, OUT_F=64, IN_E=32, OUT_E=64
#define BB    8
#define NN    256
#define OUTF  64
#define INE   32

using f4 = __attribute__((ext_vector_type(4))) float;

// Scratch for the node projections (1 MB total) — device globals so we do not
// depend on ws_size. Fully overwritten by node_proj every call (deterministic).
__device__ float g_node_x[BB * NN * OUTF];   // emb_node@W_node + b_node (pre-relu)
__device__ float g_relu_sx[BB * NN * OUTF];  // relu(emb_node@W_nodes + b_nodes)

static __device__ __forceinline__ f4 relu4(f4 v) {
    f4 r;
    r.x = fmaxf(v.x, 0.f); r.y = fmaxf(v.y, 0.f);
    r.z = fmaxf(v.z, 0.f); r.w = fmaxf(v.w, 0.f);
    return r;
}

// ---------------------------------------------------------------------------
// Kernel 1: node projections. 128 blocks x 256 threads, 16 rows per block
// (vs 4 in R6: W-staging HBM traffic 16 MB -> 4 MB, ~2 us wall).
// ---------------------------------------------------------------------------
__global__ __launch_bounds__(256) void node_proj(
    const float* __restrict__ emb_node,  // [B*N, 64]
    const float* __restrict__ W1, const float* __restrict__ b1,
    const float* __restrict__ W2, const float* __restrict__ b2)
{
    __shared__ float sW1[64][64];
    __shared__ float sW2[64][64];
    __shared__ float sE[16][64];

    const int tid = threadIdx.x;

    const f4* w1v = (const f4*)W1;
    const f4* w2v = (const f4*)W2;
    f4* s1 = (f4*)&sW1[0][0];
    f4* s2 = (f4*)&sW2[0][0];
#pragma unroll
    for (int i = 0; i < 4; ++i) {
        s1[tid + i * 256] = w1v[tid + i * 256];
        s2[tid + i * 256] = w2v[tid + i * 256];
    }
    const int row0 = blockIdx.x * 16;
    ((f4*)&sE[0][0])[tid] = ((const f4*)(emb_node + row0 * 64))[tid];  // 256 f4 = 16 rows
    __syncthreads();

    const int s = tid >> 6;    // 0..3
    const int f = tid & 63;    // output feature
    float a1[4], a2[4];
    const float bb1 = b1[f], bb2 = b2[f];
#pragma unroll
    for (int j = 0; j < 4; ++j) { a1[j] = bb1; a2[j] = bb2; }
#pragma unroll
    for (int k = 0; k < 64; ++k) {
        const float w1 = sW1[k][f];
        const float w2 = sW2[k][f];
#pragma unroll
        for (int j = 0; j < 4; ++j) {
            const float e = sE[s + 4 * j][k];   // broadcast read
            a1[j] = fmaf(e, w1, a1[j]);
            a2[j] = fmaf(e, w2, a2[j]);
        }
    }
#pragma unroll
    for (int j = 0; j < 4; ++j) {
        const int row = row0 + s + 4 * j;
        g_node_x[row * 64 + f]  = a1[j];             // pre-relu (used inside einsum)
        g_relu_sx[row * 64 + f] = fmaxf(a2[j], 0.f);
    }
}

// ---------------------------------------------------------------------------
// Kernel 2: SOFTWARE-PIPELINED edge GEMM + aggregation.
// 1024 blocks x 256 threads (4 waves). Block i owns bn0=2i and bn1=2i+1,
// processed as 4 half-tiles T0=(bn0,h0) T1=(bn0,h1) T2=(bn1,h0) T3=(bn1,h1).
// Per tile: issue NEXT tile's global loads (4 f4/thread, nontemporal) BEFORE
// the GEMM; after the read-fence barrier, ds_write them; barrier; repeat.
// => HBM load stream for t+1 overlaps compute of t (breaks phase lockstep).
// LDS 28672 B -> 5 blocks/CU; launch_bounds(256,5) caps VGPR at 102 (est ~90,
// no spills). All LDS patterns at their conflict floors (staging f4 writes
// 8/bank-group; e-reads 4-addr x 16-lane broadcast; w-reads 16-addr 2-way).
// agg accumulates over both halves of a bn in registers; reduce via shfl
// (lane bits 4,5) + sRed across 4 waves; node_out written by owning block.
// ---------------------------------------------------------------------------
__global__ __launch_bounds__(256, 5) void edge_agg(
    const float* __restrict__ A,         // [B,N,N]
    const float* __restrict__ emb_edge,  // [B,N,N,32]
    const float* __restrict__ W_edge,    // [32,64]
    const float* __restrict__ b_edge,    // [64]
    float* __restrict__ node_out,        // [B,N,64]
    float* __restrict__ edge_out)        // [B,N,N,64]
{
    __shared__ __align__(16) float sE[128 * 36];  // 18432 B, half-tile, 36-pad
    __shared__ __align__(16) float sW[32 * 64];   //  8192 B (live all tiles)
    __shared__ float sA[256];                     //  1024 B (current bn's A row)
    __shared__ float sRed[4][64];                 //  1024 B

    const int tid  = threadIdx.x;
    const int bn0  = blockIdx.x * 2;       // bn0 even => bn0, bn0+1 share b
    const int b    = bn0 >> 8;
    const int lane = tid & 63;
    const int wv   = tid >> 6;             // wave 0..3
    const int fg   = tid & 15;             // f-group (16 x 4f)
    const int mg   = tid >> 4;             // m-group within half-tile (16 x 8 rows)
    const int f0   = fg * 4;

    // ---- stage W (512 f4, 2/thread); bias in regs ----
    ((f4*)sW)[tid]       = ((const f4*)W_edge)[tid];
    ((f4*)sW)[tid + 256] = ((const f4*)W_edge)[tid + 256];
    const f4 bias = *(const f4*)(b_edge + f0);

    // ---- prologue: prefetch T0=(bn0,h0) + A row of bn0, write to LDS ----
    {
        const f4* src = (const f4*)(emb_edge + (size_t)bn0 * (NN * INE)); // h0: first 1024 f4
        f4 p0 = __builtin_nontemporal_load(src + tid);
        f4 p1 = __builtin_nontemporal_load(src + tid + 256);
        f4 p2 = __builtin_nontemporal_load(src + tid + 512);
        f4 p3 = __builtin_nontemporal_load(src + tid + 768);
        f4 pa;
        if (tid < 64) pa = ((const f4*)(A + (size_t)bn0 * NN))[tid];
#pragma unroll
        for (int j = 0; j < 4; ++j) {
            const int i = tid + j * 256;
            const f4 v = (j == 0) ? p0 : (j == 1) ? p1 : (j == 2) ? p2 : p3;
            *(f4*)&sE[(i >> 3) * 36 + (i & 7) * 4] = v;
        }
        if (tid < 64) ((f4*)sA)[tid] = pa;
    }
    __syncthreads();

    const float* nx = g_node_x + b * (NN * OUTF);
    f4 agg; agg.x = 0.f; agg.y = 0.f; agg.z = 0.f; agg.w = 0.f;

#pragma unroll
    for (int t = 0; t < 4; ++t) {
        const int h  = t & 1;
        const int bn = bn0 + (t >> 1);

        // ---- issue NEXT tile's global loads (overlap with this GEMM) ----
        f4 q0, q1, q2, q3, qa;
        if (t < 3) {
            const int nbn = bn0 + ((t + 1) >> 1);
            const int nh  = (t + 1) & 1;
            const f4* nsrc = (const f4*)(emb_edge
                             + ((size_t)nbn * NN + (size_t)nh * 128) * INE);
            q0 = __builtin_nontemporal_load(nsrc + tid);
            q1 = __builtin_nontemporal_load(nsrc + tid + 256);
            q2 = __builtin_nontemporal_load(nsrc + tid + 512);
            q3 = __builtin_nontemporal_load(nsrc + tid + 768);
            if (t == 1 && tid < 64)
                qa = ((const f4*)(A + (size_t)(bn0 + 1) * NN))[tid];
        }

        // ---- register-tiled GEMM over the staged half-tile ----
        f4 acc[8];
#pragma unroll
        for (int i = 0; i < 8; ++i) acc[i] = bias;
#pragma unroll
        for (int k4 = 0; k4 < 8; ++k4) {
            f4 w[4];
#pragma unroll
            for (int kk = 0; kk < 4; ++kk)
                w[kk] = *(const f4*)&sW[(k4 * 4 + kk) * 64 + f0];
#pragma unroll
            for (int i = 0; i < 8; ++i) {
                const f4 e = *(const f4*)&sE[(mg + i * 16) * 36 + k4 * 4];
                acc[i] += e.x * w[0];
                acc[i] += e.y * w[1];
                acc[i] += e.z * w[2];
                acc[i] += e.w * w[3];
            }
        }

        // ---- epilogue: relu f4 nt store + weighted agg against node_x ----
        float* eo = edge_out + (size_t)bn * (NN * OUTF);
#pragma unroll
        for (int i = 0; i < 8; ++i) {
            const int lm = mg + i * 16;
            const int m  = h * 128 + lm;
            const float a = sA[m];                           // LDS broadcast
            const f4 nxv = *(const f4*)&nx[m * OUTF + f0];   // L2-hot
            const f4 v   = acc[i];                           // pre-relu edge_x
            __builtin_nontemporal_store(relu4(v), (f4*)&eo[(size_t)m * OUTF + f0]);
            agg.x = fmaf(a * v.x, nxv.x, agg.x);
            agg.y = fmaf(a * v.y, nxv.y, agg.y);
            agg.z = fmaf(a * v.z, nxv.z, agg.z);
            agg.w = fmaf(a * v.w, nxv.w, agg.w);
        }

        // ---- at bn end: wave-reduce agg (lane bits 4,5) into sRed ----
        if (h == 1) {
            f4 r = agg;
#pragma unroll
            for (int s = 16; s < 64; s <<= 1) {
                r.x += __shfl_xor(r.x, s);
                r.y += __shfl_xor(r.y, s);
                r.z += __shfl_xor(r.z, s);
                r.w += __shfl_xor(r.w, s);
            }
            if (lane < 16) *(f4*)&sRed[wv][lane * 4] = r;
        }
        __syncthreads();                 // E-buf reads + sRed writes complete

        if (t < 3) {                     // ds_write the prefetched tile
#pragma unroll
            for (int j = 0; j < 4; ++j) {
                const int i = tid + j * 256;
                const f4 v = (j == 0) ? q0 : (j == 1) ? q1 : (j == 2) ? q2 : q3;
                *(f4*)&sE[(i >> 3) * 36 + (i & 7) * 4] = v;
            }
            if (t == 1 && tid < 64) ((f4*)sA)[tid] = qa;
        }
        __syncthreads();                 // new tile (and sRed) visible

        if (h == 1) {
            if (tid < 64) {              // finish node_out for this bn
                const float s = sRed[0][tid] + sRed[1][tid]
                              + sRed[2][tid] + sRed[3][tid];
                node_out[bn * OUTF + tid] = fmaxf(s, 0.f)
                                          + g_relu_sx[bn * OUTF + tid];
            }
            agg.x = 0.f; agg.y = 0.f; agg.z = 0.f; agg.w = 0.f;
        }
    }
}

// ---------------------------------------------------------------------------
extern "C" void kernel_launch(void* const* d_in, const int* in_sizes, int n_in,
                              void* d_out, int out_size, void* d_ws, size_t ws_size,
                              hipStream_t stream) {
    const float* A        = (const float*)d_in[0];
    const float* emb_node = (const float*)d_in[1];
    const float* emb_edge = (const float*)d_in[2];
    const float* W_node   = (const float*)d_in[3];
    const float* b_node   = (const float*)d_in[4];
    const float* W_nodes  = (const float*)d_in[5];
    const float* b_nodes  = (const float*)d_in[6];
    const float* W_edge   = (const float*)d_in[7];
    const float* b_edge   = (const float*)d_in[8];

    float* node_out = (float*)d_out;                 // [8,256,64]
    float* edge_out = node_out + BB * NN * OUTF;     // [8,256,256,64]

    node_proj<<<(BB * NN) / 16, 256, 0, stream>>>(emb_node, W_node, b_node,
                                                  W_nodes, b_nodes);
    edge_agg<<<(BB * NN) / 2, 256, 0, stream>>>(A, emb_edge, W_edge, b_edge,
                                                node_out, edge_out);
}

// Round 8
// 49.821 us; speedup vs baseline: 1.9372x; 1.9372x over previous
//
#include <hip/hip_runtime.h>

// Problem constants (fixed by the reference):
//   B=8, N=256, IN_F=64, OUT_F=64, IN_E=32, OUT_E=64
#define BB    8
#define NN    256
#define OUTF  64
#define INE   32

using f4     = __attribute__((ext_vector_type(4))) float;
using f32x4  = __attribute__((ext_vector_type(4))) float;
using bf16x8 = __attribute__((ext_vector_type(8))) short;  // 8 bf16 = 4 VGPRs

// Device-global scratch; fully overwritten every call (deterministic).
__device__ float          g_node_x[BB * NN * OUTF];   // emb_node@W_node + b (pre-relu)
__device__ float          g_relu_sx[BB * NN * OUTF];  // relu(emb_node@W_nodes + b)
__device__ unsigned short g_wtb[OUTF * INE];          // W_edge^T as bf16, [f][k]

// f32 -> bf16 round-to-nearest-even (verified in R2-R6, absmax pass).
static __device__ __forceinline__ unsigned short f2bf(float x) {
    unsigned u = __builtin_bit_cast(unsigned, x);
    u += 0x7fffu + ((u >> 16) & 1u);
    return (unsigned short)(u >> 16);
}

static __device__ __forceinline__ f4 relu4(f4 v) {
    f4 r;
    r.x = fmaxf(v.x, 0.f); r.y = fmaxf(v.y, 0.f);
    r.z = fmaxf(v.z, 0.f); r.w = fmaxf(v.w, 0.f);
    return r;
}

// ---------------------------------------------------------------------------
// Kernel 1: node projections (16 rows/block) + one-time W_edge^T bf16 prep.
// ---------------------------------------------------------------------------
__global__ __launch_bounds__(256) void node_proj(
    const float* __restrict__ emb_node,  // [B*N, 64]
    const float* __restrict__ W1, const float* __restrict__ b1,
    const float* __restrict__ W2, const float* __restrict__ b2,
    const float* __restrict__ W_edge)    // [32, 64]
{
    __shared__ float sW1[64][64];
    __shared__ float sW2[64][64];
    __shared__ float sE[16][64];

    const int tid = threadIdx.x;

    if (blockIdx.x == 0) {               // prep W_edge^T bf16 (2 KB), L2-hot later
        const int f  = tid >> 2;
        const int k0 = (tid & 3) * 8;
#pragma unroll
        for (int j = 0; j < 8; ++j)
            g_wtb[f * INE + k0 + j] = f2bf(W_edge[(k0 + j) * OUTF + f]);
    }

    const f4* w1v = (const f4*)W1;
    const f4* w2v = (const f4*)W2;
    f4* s1 = (f4*)&sW1[0][0];
    f4* s2 = (f4*)&sW2[0][0];
#pragma unroll
    for (int i = 0; i < 4; ++i) {
        s1[tid + i * 256] = w1v[tid + i * 256];
        s2[tid + i * 256] = w2v[tid + i * 256];
    }
    const int row0 = blockIdx.x * 16;
    ((f4*)&sE[0][0])[tid] = ((const f4*)(emb_node + row0 * 64))[tid];
    __syncthreads();

    const int s = tid >> 6;    // 0..3
    const int f = tid & 63;
    float a1[4], a2[4];
    const float bb1 = b1[f], bb2 = b2[f];
#pragma unroll
    for (int j = 0; j < 4; ++j) { a1[j] = bb1; a2[j] = bb2; }
#pragma unroll
    for (int k = 0; k < 64; ++k) {
        const float w1 = sW1[k][f];
        const float w2 = sW2[k][f];
#pragma unroll
        for (int j = 0; j < 4; ++j) {
            const float e = sE[s + 4 * j][k];
            a1[j] = fmaf(e, w1, a1[j]);
            a2[j] = fmaf(e, w2, a2[j]);
        }
    }
#pragma unroll
    for (int j = 0; j < 4; ++j) {
        const int row = row0 + s + 4 * j;
        g_node_x[row * 64 + f]  = a1[j];
        g_relu_sx[row * 64 + f] = fmaxf(a2[j], 0.f);
    }
}

// ---------------------------------------------------------------------------
// Kernel 2: NO-STAGING MFMA. 2048 blocks x 256 threads (4 waves), LDS = 1 KB.
// Wave w owns rows [64w, 64w+64) of its (b,n) tile; per mt (16 rows):
//   efrag: E[m][q*8..q*8+7] as TWO CACHED f4 loads (32B contiguous per lane;
//          L1/L2 line absorbs the lo/hi split — no nt, the R3 mistake)
//   4x mfma_f32_16x16x32_bf16(wfrag[ft], efrag, bias[ft])  [R4-verified maps]
//   fused epilogue: relu f4 nt store (full sectors: 16 rows x 64B per instr)
//   + agg fma against L2-hot node_x.
// No barrier until the final 2-level reduce. NO min-waves launch bound —
// the R5/R7 spills came from my own caps; let the allocator keep ~100 VGPR.
// ---------------------------------------------------------------------------
__global__ __launch_bounds__(256) void edge_agg(
    const float* __restrict__ A,         // [B,N,N]
    const float* __restrict__ emb_edge,  // [B,N,N,32]
    const float* __restrict__ b_edge,    // [64]
    float* __restrict__ node_out,        // [B,N,64]
    float* __restrict__ edge_out)        // [B,N,N,64]
{
    __shared__ float sRed[4][64];        // only LDS in the kernel

    const int tid  = threadIdx.x;
    const int bn   = blockIdx.x;         // b*256 + n
    const int b    = bn >> 8;
    const int wave = tid >> 6;
    const int lane = tid & 63;
    const int c    = lane & 15;          // m within 16-tile / f-row of W^T
    const int q    = lane >> 4;          // k-quad & f-quad selector
    const int wbase = wave * 64;

    // ---- L2-hot constants: W^T fragments + bias (R4-verified layout) ----
    bf16x8 wfrag[4];
    f4     bias[4];
#pragma unroll
    for (int ft = 0; ft < 4; ++ft) {
        wfrag[ft] = *(const bf16x8*)&g_wtb[(ft * 16 + c) * INE + q * 8];
        bias[ft]  = *(const f4*)&b_edge[ft * 16 + q * 4];
    }

    const float* ebase = emb_edge + (size_t)bn * (NN * INE);
    const float* Arow  = A + (size_t)bn * NN;
    const float* nx    = g_node_x + b * (NN * OUTF);
    float*       eo    = edge_out + (size_t)bn * (NN * OUTF);

    f4 agg[4];
#pragma unroll
    for (int ft = 0; ft < 4; ++ft) { agg[ft].x = 0.f; agg[ft].y = 0.f; agg[ft].z = 0.f; agg[ft].w = 0.f; }

#pragma unroll
    for (int mt = 0; mt < 4; ++mt) {
        const int m = wbase + mt * 16 + c;

        // E fragment: 32B contiguous cached load (lo/hi share the cache line)
        const float* rp = ebase + m * INE + q * 8;
        const f4 lo = *(const f4*)rp;
        const f4 hi = *(const f4*)(rp + 4);
        bf16x8 ef;
        ef[0] = (short)f2bf(lo.x); ef[1] = (short)f2bf(lo.y);
        ef[2] = (short)f2bf(lo.z); ef[3] = (short)f2bf(lo.w);
        ef[4] = (short)f2bf(hi.x); ef[5] = (short)f2bf(hi.y);
        ef[6] = (short)f2bf(hi.z); ef[7] = (short)f2bf(hi.w);

        const float a = Arow[m];                       // 64B segment, L1-hot

        f32x4 acc[4];
#pragma unroll
        for (int ft = 0; ft < 4; ++ft)
            acc[ft] = __builtin_amdgcn_mfma_f32_16x16x32_bf16(
                wfrag[ft], ef, bias[ft], 0, 0, 0);

        // fused epilogue: lane holds 4 consecutive f for row m
#pragma unroll
        for (int ft = 0; ft < 4; ++ft) {
            const int fb  = ft * 16 + q * 4;
            const f4  v   = acc[ft];                         // pre-relu edge_x
            const f4  nxv = *(const f4*)&nx[m * OUTF + fb];  // L2-hot
            __builtin_nontemporal_store(relu4(v), (f4*)&eo[(size_t)m * OUTF + fb]);
            agg[ft].x = fmaf(a * v.x, nxv.x, agg[ft].x);
            agg[ft].y = fmaf(a * v.y, nxv.y, agg[ft].y);
            agg[ft].z = fmaf(a * v.z, nxv.z, agg[ft].z);
            agg[ft].w = fmaf(a * v.w, nxv.w, agg[ft].w);
        }
    }

    // ---- reduce over the 16 m-columns (lane bits 0..3 == c) ----
#pragma unroll
    for (int ft = 0; ft < 4; ++ft) {
#pragma unroll
        for (int s = 1; s < 16; s <<= 1) {
            agg[ft].x += __shfl_xor(agg[ft].x, s);
            agg[ft].y += __shfl_xor(agg[ft].y, s);
            agg[ft].z += __shfl_xor(agg[ft].z, s);
            agg[ft].w += __shfl_xor(agg[ft].w, s);
        }
    }
    if (c == 0) {
#pragma unroll
        for (int ft = 0; ft < 4; ++ft)
            *(f4*)&sRed[wave][ft * 16 + q * 4] = agg[ft];
    }
    __syncthreads();

    // ---- reduce across 4 waves, add relu(node_sx), store node_out ----
    if (tid < 64) {
        float s = sRed[0][tid] + sRed[1][tid] + sRed[2][tid] + sRed[3][tid];
        node_out[bn * OUTF + tid] = fmaxf(s, 0.f) + g_relu_sx[bn * OUTF + tid];
    }
}

// ---------------------------------------------------------------------------
extern "C" void kernel_launch(void* const* d_in, const int* in_sizes, int n_in,
                              void* d_out, int out_size, void* d_ws, size_t ws_size,
                              hipStream_t stream) {
    const float* A        = (const float*)d_in[0];
    const float* emb_node = (const float*)d_in[1];
    const float* emb_edge = (const float*)d_in[2];
    const float* W_node   = (const float*)d_in[3];
    const float* b_node   = (const float*)d_in[4];
    const float* W_nodes  = (const float*)d_in[5];
    const float* b_nodes  = (const float*)d_in[6];
    const float* W_edge   = (const float*)d_in[7];
    const float* b_edge   = (const float*)d_in[8];

    float* node_out = (float*)d_out;                 // [8,256,64]
    float* edge_out = node_out + BB * NN * OUTF;     // [8,256,256,64]

    node_proj<<<(BB * NN) / 16, 256, 0, stream>>>(emb_node, W_node, b_node,
                                                  W_nodes, b_nodes, W_edge);
    edge_agg<<<BB * NN, 256, 0, stream>>>(A, emb_edge, b_edge, node_out, edge_out);
}

// Round 9
// 48.103 us; speedup vs baseline: 2.0064x; 1.0357x over previous
//
#include <hip/hip_runtime.h>

// Problem constants (fixed by the reference):
//   B=8, N=256, IN_F=64, OUT_F=64, IN_E=32, OUT_E=64
#define BB    8
#define NN    256
#define OUTF  64
#define INE   32

using f4     = __attribute__((ext_vector_type(4))) float;
using f32x4  = __attribute__((ext_vector_type(4))) float;
using bf16x8 = __attribute__((ext_vector_type(8))) short;  // 8 bf16 = 4 VGPRs

// Device-global scratch; fully overwritten every call (deterministic).
__device__ float          g_node_x[BB * NN * OUTF];   // emb_node@W_node + b (pre-relu)
__device__ float          g_relu_sx[BB * NN * OUTF];  // relu(emb_node@W_nodes + b)
__device__ unsigned short g_wtb[OUTF * INE];          // W_edge^T as bf16, [f][k]

// f32 -> bf16 round-to-nearest-even (verified R2-R8, absmax pass).
static __device__ __forceinline__ unsigned short f2bf(float x) {
    unsigned u = __builtin_bit_cast(unsigned, x);
    u += 0x7fffu + ((u >> 16) & 1u);
    return (unsigned short)(u >> 16);
}

static __device__ __forceinline__ bf16x8 cvt8(f4 lo, f4 hi) {
    bf16x8 e;
    e[0] = (short)f2bf(lo.x); e[1] = (short)f2bf(lo.y);
    e[2] = (short)f2bf(lo.z); e[3] = (short)f2bf(lo.w);
    e[4] = (short)f2bf(hi.x); e[5] = (short)f2bf(hi.y);
    e[6] = (short)f2bf(hi.z); e[7] = (short)f2bf(hi.w);
    return e;
}

static __device__ __forceinline__ f4 relu4(f4 v) {
    f4 r;
    r.x = fmaxf(v.x, 0.f); r.y = fmaxf(v.y, 0.f);
    r.z = fmaxf(v.z, 0.f); r.w = fmaxf(v.w, 0.f);
    return r;
}

// ---------------------------------------------------------------------------
// Kernel 1: node projections (16 rows/block) + one-time W_edge^T bf16 prep.
// (unchanged from R8)
// ---------------------------------------------------------------------------
__global__ __launch_bounds__(256) void node_proj(
    const float* __restrict__ emb_node,  // [B*N, 64]
    const float* __restrict__ W1, const float* __restrict__ b1,
    const float* __restrict__ W2, const float* __restrict__ b2,
    const float* __restrict__ W_edge)    // [32, 64]
{
    __shared__ float sW1[64][64];
    __shared__ float sW2[64][64];
    __shared__ float sE[16][64];

    const int tid = threadIdx.x;

    if (blockIdx.x == 0) {               // prep W_edge^T bf16 (2 KB), L2-hot later
        const int f  = tid >> 2;
        const int k0 = (tid & 3) * 8;
#pragma unroll
        for (int j = 0; j < 8; ++j)
            g_wtb[f * INE + k0 + j] = f2bf(W_edge[(k0 + j) * OUTF + f]);
    }

    const f4* w1v = (const f4*)W1;
    const f4* w2v = (const f4*)W2;
    f4* s1 = (f4*)&sW1[0][0];
    f4* s2 = (f4*)&sW2[0][0];
#pragma unroll
    for (int i = 0; i < 4; ++i) {
        s1[tid + i * 256] = w1v[tid + i * 256];
        s2[tid + i * 256] = w2v[tid + i * 256];
    }
    const int row0 = blockIdx.x * 16;
    ((f4*)&sE[0][0])[tid] = ((const f4*)(emb_node + row0 * 64))[tid];
    __syncthreads();

    const int s = tid >> 6;    // 0..3
    const int f = tid & 63;
    float a1[4], a2[4];
    const float bb1 = b1[f], bb2 = b2[f];
#pragma unroll
    for (int j = 0; j < 4; ++j) { a1[j] = bb1; a2[j] = bb2; }
#pragma unroll
    for (int k = 0; k < 64; ++k) {
        const float w1 = sW1[k][f];
        const float w2 = sW2[k][f];
#pragma unroll
        for (int j = 0; j < 4; ++j) {
            const float e = sE[s + 4 * j][k];
            a1[j] = fmaf(e, w1, a1[j]);
            a2[j] = fmaf(e, w2, a2[j]);
        }
    }
#pragma unroll
    for (int j = 0; j < 4; ++j) {
        const int row = row0 + s + 4 * j;
        g_node_x[row * 64 + f]  = a1[j];
        g_relu_sx[row * 64 + f] = fmaxf(a2[j], 0.f);
    }
}

// ---------------------------------------------------------------------------
// Kernel 2: NO-STAGING MFMA with BOUNDED 2-deep pipeline.
// 2048 blocks x 256 threads (4 waves), LDS = 1 KB. Wave w owns rows
// [64w, 64w+64); per mt (16 rows): cached 32B E-row loads -> bf16 frag ->
// 4x mfma_f32_16x16x32_bf16 (R4-verified swapped-operand maps) -> fused
// epilogue (relu f4 PLAIN store — L2 merges the 64B half-lines — + agg fma
// against L2-hot node_x).
// R8 lesson: unbounded unroll let the compiler pipeline all 4 mt (4x16 AGPR
// + hoisted operands -> ~3 waves/SIMD -> latency-bound at 27% occupancy).
// Here mt+1's loads are issued manually BEFORE mt's MFMA, and a
// sched_barrier(0) after each mt epilogue pins the 2-deep structure:
// one acc set (16 AGPR) + one prefetch set live => ~4-5 waves/SIMD.
// ---------------------------------------------------------------------------
__global__ __launch_bounds__(256) void edge_agg(
    const float* __restrict__ A,         // [B,N,N]
    const float* __restrict__ emb_edge,  // [B,N,N,32]
    const float* __restrict__ b_edge,    // [64]
    float* __restrict__ node_out,        // [B,N,64]
    float* __restrict__ edge_out)        // [B,N,N,64]
{
    __shared__ float sRed[4][64];        // only LDS in the kernel

    const int tid  = threadIdx.x;
    const int bn   = blockIdx.x;         // b*256 + n
    const int b    = bn >> 8;
    const int wave = tid >> 6;
    const int lane = tid & 63;
    const int c    = lane & 15;          // m within 16-tile / f-row of W^T
    const int q    = lane >> 4;          // k-quad & f-quad selector
    const int wbase = wave * 64;

    // ---- L2-hot constants: W^T fragments + bias (R4-verified layout) ----
    bf16x8 wfrag[4];
    f4     bias[4];
#pragma unroll
    for (int ft = 0; ft < 4; ++ft) {
        wfrag[ft] = *(const bf16x8*)&g_wtb[(ft * 16 + c) * INE + q * 8];
        bias[ft]  = *(const f4*)&b_edge[ft * 16 + q * 4];
    }

    const float* ebase = emb_edge + (size_t)bn * (NN * INE);
    const float* Arow  = A + (size_t)bn * NN;
    const float* nx    = g_node_x + b * (NN * OUTF);
    float*       eo    = edge_out + (size_t)bn * (NN * OUTF);

    f4 agg[4];
#pragma unroll
    for (int ft = 0; ft < 4; ++ft) { agg[ft].x = 0.f; agg[ft].y = 0.f; agg[ft].z = 0.f; agg[ft].w = 0.f; }

    // ---- prologue: issue mt=0 loads ----
    const float* rp0 = ebase + (wbase + c) * INE + q * 8;
    f4    plo = *(const f4*)rp0;         // cached: lo/hi share the line
    f4    phi = *(const f4*)(rp0 + 4);
    float pa  = Arow[wbase + c];

#pragma unroll
    for (int mt = 0; mt < 4; ++mt) {
        const int m = wbase + mt * 16 + c;

        // current tile operands
        const f4    lo = plo;
        const f4    hi = phi;
        const float a  = pa;

        // ---- issue NEXT tile's loads before this tile's compute ----
        if (mt < 3) {
            const float* rpn = ebase + (m + 16) * INE + q * 8;
            plo = *(const f4*)rpn;
            phi = *(const f4*)(rpn + 4);
            pa  = Arow[m + 16];
        }

        const bf16x8 ef = cvt8(lo, hi);

        f32x4 acc[4];
#pragma unroll
        for (int ft = 0; ft < 4; ++ft)
            acc[ft] = __builtin_amdgcn_mfma_f32_16x16x32_bf16(
                wfrag[ft], ef, bias[ft], 0, 0, 0);

        // fused epilogue: lane holds 4 consecutive f for row m
#pragma unroll
        for (int ft = 0; ft < 4; ++ft) {
            const int fb  = ft * 16 + q * 4;
            const f4  v   = acc[ft];                         // pre-relu edge_x
            const f4  nxv = *(const f4*)&nx[m * OUTF + fb];  // L2-hot
            *(f4*)&eo[(size_t)m * OUTF + fb] = relu4(v);     // plain store: L2 merges
            agg[ft].x = fmaf(a * v.x, nxv.x, agg[ft].x);
            agg[ft].y = fmaf(a * v.y, nxv.y, agg[ft].y);
            agg[ft].z = fmaf(a * v.z, nxv.z, agg[ft].z);
            agg[ft].w = fmaf(a * v.w, nxv.w, agg[ft].w);
        }

        // pin the 2-deep pipeline: no cross-mt MFMA/acc duplication
        __builtin_amdgcn_sched_barrier(0);
    }

    // ---- reduce over the 16 m-columns (lane bits 0..3 == c) ----
#pragma unroll
    for (int ft = 0; ft < 4; ++ft) {
#pragma unroll
        for (int s = 1; s < 16; s <<= 1) {
            agg[ft].x += __shfl_xor(agg[ft].x, s);
            agg[ft].y += __shfl_xor(agg[ft].y, s);
            agg[ft].z += __shfl_xor(agg[ft].z, s);
            agg[ft].w += __shfl_xor(agg[ft].w, s);
        }
    }
    if (c == 0) {
#pragma unroll
        for (int ft = 0; ft < 4; ++ft)
            *(f4*)&sRed[wave][ft * 16 + q * 4] = agg[ft];
    }
    __syncthreads();

    // ---- reduce across 4 waves, add relu(node_sx), store node_out ----
    if (tid < 64) {
        float s = sRed[0][tid] + sRed[1][tid] + sRed[2][tid] + sRed[3][tid];
        node_out[bn * OUTF + tid] = fmaxf(s, 0.f) + g_relu_sx[bn * OUTF + tid];
    }
}

// ---------------------------------------------------------------------------
extern "C" void kernel_launch(void* const* d_in, const int* in_sizes, int n_in,
                              void* d_out, int out_size, void* d_ws, size_t ws_size,
                              hipStream_t stream) {
    const float* A        = (const float*)d_in[0];
    const float* emb_node = (const float*)d_in[1];
    const float* emb_edge = (const float*)d_in[2];
    const float* W_node   = (const float*)d_in[3];
    const float* b_node   = (const float*)d_in[4];
    const float* W_nodes  = (const float*)d_in[5];
    const float* b_nodes  = (const float*)d_in[6];
    const float* W_edge   = (const float*)d_in[7];
    const float* b_edge   = (const float*)d_in[8];

    float* node_out = (float*)d_out;                 // [8,256,64]
    float* edge_out = node_out + BB * NN * OUTF;     // [8,256,256,64]

    node_proj<<<(BB * NN) / 16, 256, 0, stream>>>(emb_node, W_node, b_node,
                                                  W_nodes, b_nodes, W_edge);
    edge_agg<<<BB * NN, 256, 0, stream>>>(A, emb_edge, b_edge, node_out, edge_out);
}